// Round 5
// baseline (2329.834 us; speedup 1.0000x reference)
//
#include <hip/hip_runtime.h>
#include <math.h>

#define BS 32
#define NI 196
#define NT 256
#define DD 1024

typedef unsigned int u32;
typedef __attribute__((ext_vector_type(8))) short bf16x8;
typedef __attribute__((ext_vector_type(4))) float f32x4;

// monotonic float<->uint mapping for atomic min/max over possibly-negative floats
__device__ __forceinline__ u32 fenc(float f){ u32 u = __float_as_uint(f); return (u & 0x80000000u) ? ~u : (u | 0x80000000u); }
__device__ __forceinline__ float fdec(u32 u){ return __uint_as_float((u & 0x80000000u) ? (u & 0x7fffffffu) : ~u); }

// bf16 helpers (manual RNE; inputs are finite)
__device__ __forceinline__ unsigned short f2bf(float f){
  u32 u = __float_as_uint(f);
  u32 r = (u + 0x7FFFu + ((u >> 16) & 1u)) >> 16;
  return (unsigned short)r;
}
__device__ __forceinline__ float bf2f(unsigned short h){ return __uint_as_float((u32)h << 16); }

// DPP-based butterfly add step (within 16-lane rows)
template<int CTRL>
__device__ __forceinline__ float dppadd(float x){
  int y = __builtin_amdgcn_update_dpp(0, __float_as_int(x), CTRL, 0xF, 0xF, false);
  return x + __int_as_float(y);
}
// sum over each 32-lane half of the wave
__device__ __forceinline__ float rowsum32(float x){
  x = dppadd<0xB1>(x);    // quad_perm xor1
  x = dppadd<0x4E>(x);    // quad_perm xor2
  x = dppadd<0x141>(x);   // row_half_mirror (pairs within 8)
  x = dppadd<0x128>(x);   // row_ror:8 (pairs within 16)
  x += __shfl_xor(x, 16);
  return x;
}

// ---------------- init ----------------
__global__ void init_mm_k(u32* mm){
  int t = threadIdx.x;
  if (t < 3){ mm[2*t] = 0xFFFFFFFFu; mm[2*t+1] = 0u; }
}
__global__ void zero_k(int* flags, float* wd){
  int t = threadIdx.x;
  if (t < 6*BS) flags[t] = 0;
  if (t < BS) wd[t] = 0.f;
}

// ---------------- prep: normalize rows, split to bf16 hi/lo ----------------
__global__ __launch_bounds__(256) void prep_k(const float* __restrict__ feat,
                                              const float* __restrict__ mask,
                                              unsigned short* __restrict__ hi,
                                              unsigned short* __restrict__ lo, int R){
  int b = blockIdx.y, r = blockIdx.x, t = threadIdx.x;
  size_t rowoff = ((size_t)b*R + r)*DD;
  float4 v = ((const float4*)(feat + rowoff))[t];
  float s = v.x*v.x + v.y*v.y + v.z*v.z + v.w*v.w;
  #pragma unroll
  for (int m = 32; m >= 1; m >>= 1) s += __shfl_xor(s, m);
  __shared__ float ps[4];
  if ((t & 63) == 0) ps[t >> 6] = s;
  __syncthreads();
  float tot = ps[0] + ps[1] + ps[2] + ps[3];
  float mv = mask ? mask[b*R + r] : 1.0f;
  float sc = mv / (mv * sqrtf(tot) + 1e-12f);
  float x[4] = {v.x*sc, v.y*sc, v.z*sc, v.w*sc};
  unsigned short h[4], l[4];
  #pragma unroll
  for (int i = 0; i < 4; ++i){
    h[i] = f2bf(x[i]);
    l[i] = f2bf(x[i] - bf2f(h[i]));
  }
  *(ushort4*)(hi + rowoff + t*4) = make_ushort4(h[0],h[1],h[2],h[3]);
  *(ushort4*)(lo + rowoff + t*4) = make_ushort4(l[0],l[1],l[2],l[3]);
}

// ---------------- MFMA cos GEMM: C = 1 - Xn . Yn^T  (bf16 hi/lo split) ----------------
// 128x128 tile, 256 threads (4 waves, 2x2), K=1024 step 32. LDS rows padded to 40 elems.
__global__ __launch_bounds__(256) void cosmm_k(const unsigned short* __restrict__ Xh,
                                               const unsigned short* __restrict__ Xl,
                                               const unsigned short* __restrict__ Yh,
                                               const unsigned short* __restrict__ Yl,
                                               float* __restrict__ C, int M, int N, int nTN){
  __shared__ unsigned short Ah[128*40], Al[128*40], Bh[128*40], Bl[128*40];
  int b = blockIdx.y;
  int tm = (blockIdx.x / nTN) * 128, tn = (blockIdx.x % nTN) * 128;
  int t = threadIdx.x, lane = t & 63, w = t >> 6;
  int wm = (w >> 1) * 64, wn = (w & 1) * 64;
  const unsigned short* Xhb = Xh + (size_t)b*M*DD;
  const unsigned short* Xlb = Xl + (size_t)b*M*DD;
  const unsigned short* Yhb = Yh + (size_t)b*N*DD;
  const unsigned short* Ylb = Yl + (size_t)b*N*DD;
  f32x4 acc[4][4];
  #pragma unroll
  for (int m = 0; m < 4; ++m)
    #pragma unroll
    for (int n = 0; n < 4; ++n) acc[m][n] = (f32x4){0.f,0.f,0.f,0.f};

  int sr0 = t >> 2, sc0 = (t & 3) * 8;          // staging: row, col-chunk
  int gr0 = min(tm + sr0, M-1),      gr1 = min(tm + sr0 + 64, M-1);
  int gc0 = min(tn + sr0, N-1),      gc1 = min(tn + sr0 + 64, N-1);
  const unsigned short* pa0 = Xhb + (size_t)gr0*DD + sc0;
  const unsigned short* pa1 = Xhb + (size_t)gr1*DD + sc0;
  const unsigned short* pa2 = Xlb + (size_t)gr0*DD + sc0;
  const unsigned short* pa3 = Xlb + (size_t)gr1*DD + sc0;
  const unsigned short* pb0 = Yhb + (size_t)gc0*DD + sc0;
  const unsigned short* pb1 = Yhb + (size_t)gc1*DD + sc0;
  const unsigned short* pb2 = Ylb + (size_t)gc0*DD + sc0;
  const unsigned short* pb3 = Ylb + (size_t)gc1*DD + sc0;
  int fr = lane & 15, fk = (lane >> 4) * 8;

  for (int k0 = 0; k0 < DD; k0 += 32){
    float4 a0 = *(const float4*)(pa0 + k0);
    float4 a1 = *(const float4*)(pa1 + k0);
    float4 a2 = *(const float4*)(pa2 + k0);
    float4 a3 = *(const float4*)(pa3 + k0);
    float4 b0 = *(const float4*)(pb0 + k0);
    float4 b1 = *(const float4*)(pb1 + k0);
    float4 b2 = *(const float4*)(pb2 + k0);
    float4 b3 = *(const float4*)(pb3 + k0);
    __syncthreads();
    *(float4*)&Ah[sr0*40 + sc0]      = a0;
    *(float4*)&Ah[(sr0+64)*40 + sc0] = a1;
    *(float4*)&Al[sr0*40 + sc0]      = a2;
    *(float4*)&Al[(sr0+64)*40 + sc0] = a3;
    *(float4*)&Bh[sr0*40 + sc0]      = b0;
    *(float4*)&Bh[(sr0+64)*40 + sc0] = b1;
    *(float4*)&Bl[sr0*40 + sc0]      = b2;
    *(float4*)&Bl[(sr0+64)*40 + sc0] = b3;
    __syncthreads();
    bf16x8 ah[4], al[4], bh[4], bl[4];
    #pragma unroll
    for (int m = 0; m < 4; ++m){
      int r = wm + m*16 + fr;
      ah[m] = *(bf16x8*)&Ah[r*40 + fk];
      al[m] = *(bf16x8*)&Al[r*40 + fk];
    }
    #pragma unroll
    for (int n = 0; n < 4; ++n){
      int r = wn + n*16 + fr;
      bh[n] = *(bf16x8*)&Bh[r*40 + fk];
      bl[n] = *(bf16x8*)&Bl[r*40 + fk];
    }
    #pragma unroll
    for (int m = 0; m < 4; ++m)
      #pragma unroll
      for (int n = 0; n < 4; ++n){
        acc[m][n] = __builtin_amdgcn_mfma_f32_16x16x32_bf16(ah[m], bh[n], acc[m][n], 0,0,0);
        acc[m][n] = __builtin_amdgcn_mfma_f32_16x16x32_bf16(ah[m], bl[n], acc[m][n], 0,0,0);
        acc[m][n] = __builtin_amdgcn_mfma_f32_16x16x32_bf16(al[m], bh[n], acc[m][n], 0,0,0);
      }
  }
  float* Cb = C + (size_t)b*M*N;
  #pragma unroll
  for (int m = 0; m < 4; ++m){
    int row0 = tm + wm + m*16 + ((lane >> 4) << 2);
    #pragma unroll
    for (int n = 0; n < 4; ++n){
      int col = tn + wn + n*16 + (lane & 15);
      if (col < N){
        #pragma unroll
        for (int r = 0; r < 4; ++r){
          int row = row0 + r;
          if (row < M) Cb[(size_t)row*N + col] = 1.0f - acc[m][n][r];
        }
      }
    }
  }
}

// ---------------- fp32 batched GEMM (GW loop only) ----------------
template<bool TRB, int EPI>
__global__ __launch_bounds__(256) void gemm_k(const float* __restrict__ A,
                                              const float* __restrict__ B,
                                              float* __restrict__ C,
                                              int M, int N, int K,
                                              const float* __restrict__ av,
                                              const float* __restrict__ bv){
  __shared__ float As[16][68];
  __shared__ float Bs[16][68];
  int b  = blockIdx.z;
  int r0 = blockIdx.x * 64;
  int c0 = blockIdx.y * 64;
  int t  = threadIdx.x;
  int tx = t & 15, ty = t >> 4;
  const float* Ab = A + (size_t)b * M * K;
  const float* Bb = B + (size_t)b * (size_t)N * K;
  float acc[4][4] = {{0.f}};
  int lr = t >> 2, lq = t & 3;
  for (int k0 = 0; k0 < K; k0 += 16){
    { // A tile (transposed store)
      int gr = r0 + lr, kk = k0 + lq*4;
      float4 v = make_float4(0.f,0.f,0.f,0.f);
      if (gr < M && kk + 3 < K) v = *(const float4*)(Ab + (size_t)gr*K + kk);
      As[lq*4+0][lr]=v.x; As[lq*4+1][lr]=v.y; As[lq*4+2][lr]=v.z; As[lq*4+3][lr]=v.w;
    }
    if (TRB){
      int gc = c0 + lr, kk = k0 + lq*4;
      float4 v = make_float4(0.f,0.f,0.f,0.f);
      if (gc < N && kk + 3 < K) v = *(const float4*)(Bb + (size_t)gc*K + kk);
      Bs[lq*4+0][lr]=v.x; Bs[lq*4+1][lr]=v.y; Bs[lq*4+2][lr]=v.z; Bs[lq*4+3][lr]=v.w;
    } else {
      int kr = t >> 4, cx = (t & 15) * 4;
      int gk = k0 + kr, gc = c0 + cx;
      float4 v = make_float4(0.f,0.f,0.f,0.f);
      if (gk < K && gc + 3 < N) v = *(const float4*)(Bb + (size_t)gk*N + gc);
      *(float4*)&Bs[kr][cx] = v;
    }
    __syncthreads();
    #pragma unroll
    for (int kk = 0; kk < 16; ++kk){
      float4 a4 = *(const float4*)&As[kk][ty*4];
      float4 b4 = *(const float4*)&Bs[kk][tx*4];
      float aa[4] = {a4.x, a4.y, a4.z, a4.w};
      float bb[4] = {b4.x, b4.y, b4.z, b4.w};
      #pragma unroll
      for (int i = 0; i < 4; ++i)
        #pragma unroll
        for (int j = 0; j < 4; ++j)
          acc[i][j] = fmaf(aa[i], bb[j], acc[i][j]);
    }
    __syncthreads();
  }
  #pragma unroll
  for (int i = 0; i < 4; ++i){
    int r = r0 + ty*4 + i;
    if (r >= M) continue;
    #pragma unroll
    for (int j = 0; j < 4; ++j){
      int cc = c0 + tx*4 + j;
      if (cc >= N) continue;
      float x = acc[i][j];
      if (EPI == 2) x = av[b*M + r] + bv[b*N + cc] - 2.0f*x;
      C[(size_t)b*M*N + (size_t)r*N + cc] = x;
    }
  }
}

// ---------------- global min/max ----------------
__global__ __launch_bounds__(256) void minmax_k(const float* __restrict__ X, size_t cnt, u32* __restrict__ mm){
  size_t stride = (size_t)gridDim.x * blockDim.x;
  float mn = 3.402823466e38f, mx = -3.402823466e38f;
  for (size_t i = (size_t)blockIdx.x*blockDim.x + threadIdx.x; i < cnt; i += stride){
    float v = X[i]; mn = fminf(mn, v); mx = fmaxf(mx, v);
  }
  #pragma unroll
  for (int m = 32; m >= 1; m >>= 1){ mn = fminf(mn, __shfl_xor(mn, m)); mx = fmaxf(mx, __shfl_xor(mx, m)); }
  __shared__ float smn[4], smx[4];
  int t = threadIdx.x;
  if ((t & 63) == 0){ smn[t>>6] = mn; smx[t>>6] = mx; }
  __syncthreads();
  if (t == 0){
    mn = fminf(fminf(smn[0], smn[1]), fminf(smn[2], smn[3]));
    mx = fmaxf(fmaxf(smx[0], smx[1]), fmaxf(smx[2], smx[3]));
    atomicMin(&mm[0], fenc(mn));
    atomicMax(&mm[1], fenc(mx));
  }
}

// ---------------- threshold-relu (+ optional {0,1}->{1e-5,1} mask) ----------------
__global__ __launch_bounds__(256) void thresh_k(float* __restrict__ X, const int* __restrict__ msk,
                                                size_t cnt, const u32* __restrict__ mm){
  float mn = fdec(mm[0]), mx = fdec(mm[1]);
  float thr = mn + 0.1f * (mx - mn);
  size_t stride = (size_t)gridDim.x * blockDim.x;
  for (size_t i = (size_t)blockIdx.x*blockDim.x + threadIdx.x; i < cnt; i += stride){
    float v = X[i] - thr;
    v = v > 0.f ? v : 0.f;
    if (msk) v *= (msk[i] == 1 ? 1.0f : 1e-5f);
    X[i] = v;
  }
}

// ---------------- row mean of squares ----------------
__global__ __launch_bounds__(64) void rowmeansq_k(const float* __restrict__ X, float* __restrict__ out, int R, int Cc){
  int b = blockIdx.y, r = blockIdx.x, t = threadIdx.x;
  const float* row = X + ((size_t)b*R + r) * Cc;
  float s = 0.f;
  for (int j = t; j < Cc; j += 64){ float v = row[j]; s = fmaf(v, v, s); }
  #pragma unroll
  for (int m = 32; m >= 1; m >>= 1) s += __shfl_xor(s, m);
  if (t == 0) out[b*R + r] = s / (float)Cc;
}

// ---------------- fill ----------------
__global__ void fill_k(float* __restrict__ X, size_t cnt, float val){
  size_t stride = (size_t)gridDim.x * blockDim.x;
  for (size_t i = (size_t)blockIdx.x*blockDim.x + threadIdx.x; i < cnt; i += stride) X[i] = val;
}

// ---------------- IPOT split across 8 blocks per batch ----------------
// grid (8, BS), 256 threads. Block bk owns rows [bk*25, bk*25+25) (masked).
// thread: c=t&31 (cols j=c*8..+7), R=t>>5 (local rows lr=R+8k, k<4).
// Cross-block sync per iteration: column partials -> Gp[b][parity][bk][j]
// (agent atomics), release-increment flag[b], bounded spin for 8*(it+1).
// Race-freedom: buffer half (it&1) is rewritten only at it+2, which waits for
// flag>=8*(it+2); each block increments for it+1 only after its it-read.
// Deadlock-safety: grid is 256 blocks x 256thr, <=64 VGPR, 9.2KB LDS -> fully
// co-resident; spin is bounded so a protocol bug yields wrong output, not a hang.
template<bool WD>
__global__ __launch_bounds__(256) void ipot8_k(const float* __restrict__ Cmat,
                                               float* __restrict__ Tout,
                                               float* __restrict__ distBuf,
                                               float* __restrict__ Gp,   // [BS][2][8][NT]
                                               int* __restrict__ flags){ // [BS] for this call
  __shared__ float cp[8][NT];
  __shared__ float sgm[NT];
  __shared__ float wp[4];
  int bk = blockIdx.x, b = blockIdx.y;
  int t = threadIdx.x;
  int c = t & 31, R = t >> 5;
  int r0 = bk * 25;
  const float* Cb = Cmat + (size_t)b * NI * NT;
  int* flg = flags + b;
  float* Gb = Gp + (size_t)b * 2 * 8 * NT;

  float P[4][8], T[4][8];
  bool vld[4];
  #pragma unroll
  for (int k = 0; k < 4; ++k){
    int lr = R + 8*k;
    int i = r0 + lr;
    bool ok = (lr < 25) && (i < NI);
    vld[k] = ok;
    float4 v0 = make_float4(0,0,0,0), v1 = v0;
    if (ok){ const float* p = Cb + (size_t)i*NT + c*8; v0 = *(const float4*)p; v1 = *(const float4*)(p+4); }
    float cv[8] = {v0.x,v0.y,v0.z,v0.w,v1.x,v1.y,v1.z,v1.w};
    #pragma unroll
    for (int l = 0; l < 8; ++l){
      P[k][l] = ok ? __expf(-2.0f * cv[l]) : 0.f;
      T[k][l] = ok ? 1.f : 0.f;
    }
  }
  float sl[8];
  #pragma unroll
  for (int l = 0; l < 8; ++l) sl[l] = 1.0f / (float)NT;

  for (int it = 0; it < 20; ++it){
    // Q = P*T (into T); row sums; delta (block-local rows)
    float dl[4];
    #pragma unroll
    for (int k = 0; k < 4; ++k){
      float a = 0.f;
      #pragma unroll
      for (int l = 0; l < 8; ++l){
        float q = P[k][l] * T[k][l];
        T[k][l] = q;
        a = fmaf(q, sl[l], a);
      }
      dl[k] = a;
    }
    #pragma unroll
    for (int k = 0; k < 4; ++k){
      float r = rowsum32(dl[k]);
      dl[k] = vld[k] ? __builtin_amdgcn_rcpf((float)NI * r) : 0.f;
    }
    // column partials (local rows)
    float cpl[8];
    #pragma unroll
    for (int l = 0; l < 8; ++l) cpl[l] = 0.f;
    #pragma unroll
    for (int k = 0; k < 4; ++k)
      #pragma unroll
      for (int l = 0; l < 8; ++l) cpl[l] = fmaf(T[k][l], dl[k], cpl[l]);
    *(float4*)&cp[R][c*8]     = make_float4(cpl[0],cpl[1],cpl[2],cpl[3]);
    *(float4*)&cp[R][c*8 + 4] = make_float4(cpl[4],cpl[5],cpl[6],cpl[7]);
    __syncthreads();
    float* Gcur = Gb + (size_t)(it & 1) * 8 * NT;
    {
      float s = ((cp[0][t]+cp[1][t])+(cp[2][t]+cp[3][t]))+((cp[4][t]+cp[5][t])+(cp[6][t]+cp[7][t]));
      __hip_atomic_store(&Gcur[bk*NT + t], s, __ATOMIC_RELAXED, __HIP_MEMORY_SCOPE_AGENT);
    }
    __syncthreads();   // all 256 stores drained (vmcnt) before signaling
    if (t == 0){
      __hip_atomic_fetch_add(flg, 1, __ATOMIC_RELEASE, __HIP_MEMORY_SCOPE_AGENT);
      long guard = 0;
      while (__hip_atomic_load(flg, __ATOMIC_ACQUIRE, __HIP_MEMORY_SCOPE_AGENT) < 8*(it+1)){
        if (++guard > 200000000L) break;   // bounded: protocol bug -> wrong output, not hang
      }
    }
    __syncthreads();
    // sigma_j for j = t (identical order in every block -> deterministic)
    {
      float s = 0.f;
      #pragma unroll
      for (int p = 0; p < 8; ++p)
        s += __hip_atomic_load(&Gcur[p*NT + t], __ATOMIC_RELAXED, __HIP_MEMORY_SCOPE_AGENT);
      sgm[t] = __builtin_amdgcn_rcpf((float)NT * s);
    }
    __syncthreads();
    float4 g0 = *(const float4*)&sgm[c*8];
    float4 g1 = *(const float4*)&sgm[c*8 + 4];
    sl[0]=g0.x; sl[1]=g0.y; sl[2]=g0.z; sl[3]=g0.w;
    sl[4]=g1.x; sl[5]=g1.y; sl[6]=g1.z; sl[7]=g1.w;
    #pragma unroll
    for (int k = 0; k < 4; ++k)
      #pragma unroll
      for (int l = 0; l < 8; ++l) T[k][l] *= dl[k] * sl[l];
  }
  // write T (local rows)
  float* To = Tout + (size_t)b * NI * NT;
  #pragma unroll
  for (int k = 0; k < 4; ++k){
    if (vld[k]){
      int i = r0 + R + 8*k;
      float* p = To + (size_t)i*NT + c*8;
      *(float4*)p     = make_float4(T[k][0],T[k][1],T[k][2],T[k][3]);
      *(float4*)(p+4) = make_float4(T[k][4],T[k][5],T[k][6],T[k][7]);
    }
  }
  if (WD){
    float a = 0.f;
    #pragma unroll
    for (int k = 0; k < 4; ++k){
      if (vld[k]){
        int i = r0 + R + 8*k;
        const float* p = Cb + (size_t)i*NT + c*8;
        float4 v0 = *(const float4*)p, v1 = *(const float4*)(p+4);
        float cv[8] = {v0.x,v0.y,v0.z,v0.w,v1.x,v1.y,v1.z,v1.w};
        #pragma unroll
        for (int l = 0; l < 8; ++l) a = fmaf(cv[l], T[k][l], a);
      }
    }
    #pragma unroll
    for (int m = 32; m >= 1; m >>= 1) a += __shfl_xor(a, m);
    if ((t & 63) == 0) wp[t >> 6] = a;
    __syncthreads();
    if (t == 0){
      float s = wp[0]+wp[1]+wp[2]+wp[3];
      atomicAdd(&distBuf[b], -s);
    }
  }
}

// ---------------- GW final distance + copy gamma to output ----------------
__global__ __launch_bounds__(256) void gwdist_k(const float* __restrict__ Cg, const float* __restrict__ gam,
                                                float* __restrict__ outT, float* __restrict__ gwd){
  int b = blockIdx.x, t = threadIdx.x;
  const float* cb = Cg + (size_t)b*NI*NT;
  const float* gb = gam + (size_t)b*NI*NT;
  float* ob = outT + (size_t)b*NI*NT;
  float a = 0.f;
  for (int i = t; i < NI*NT; i += 256){
    float g = gb[i];
    a = fmaf(cb[i], g, a);
    ob[i] = g;
  }
  #pragma unroll
  for (int m = 32; m >= 1; m >>= 1) a += __shfl_xor(a, m);
  __shared__ float ps[4];
  if ((t & 63) == 0) ps[t>>6] = a;
  __syncthreads();
  if (t == 0) gwd[b] = ps[0]+ps[1]+ps[2]+ps[3];
}

// ---------------- final scalar ----------------
__global__ void fin_k(const float* __restrict__ wd, const float* __restrict__ gwd, float* __restrict__ out){
  int t = threadIdx.x;
  float w = (t < BS) ? wd[t] : 0.f;
  float g = (t < BS) ? gwd[t] : 0.f;
  #pragma unroll
  for (int m = 32; m >= 1; m >>= 1){ w += __shfl_xor(w, m); g += __shfl_xor(g, m); }
  if (t == 0) out[0] = 0.1f * (g / (float)BS) + 0.1f * (w / (float)BS);
}

extern "C" void kernel_launch(void* const* d_in, const int* in_sizes, int n_in,
                              void* d_out, int out_size, void* d_ws, size_t ws_size,
                              hipStream_t stream){
  const float* img  = (const float*)d_in[0];   // (32,196,1024)
  const float* tok  = (const float*)d_in[1];   // (32,256,1024)
  const float* tmsk = (const float*)d_in[2];   // (32,256)
  const int*   tdm  = (const int*)d_in[3];     // (32,256,256)
  const int*   irm  = (const int*)d_in[4];     // (32,196,196)
  float* out = (float*)d_out;                  // [twd, T_wd, T_gwd]

  float* ws = (float*)d_ws;
  size_t off = 0;
  float* cosIT = ws + off; off += (size_t)BS*NI*NT;
  float* Cs    = ws + off; off += (size_t)BS*NI*NI;
  float* Ct    = ws + off; off += (size_t)BS*NT*NT;
  // X region (bf16 hi/lo of img): 2 * BS*NI*DD ushorts = BS*NI*DD float-slots
  float* Xreg  = ws + off; off += (size_t)BS*NI*DD;
  // gamma/Cgam/G1 alias the X region (X dead after cos GEMMs, gamma born after)
  float* gamma = Xreg;
  float* Cgam  = Xreg + (size_t)BS*NI*NT;
  float* G1    = Xreg + (size_t)2*BS*NI*NT;
  unsigned short* Xh = (unsigned short*)Xreg;
  unsigned short* Xl = Xh + (size_t)BS*NI*DD;
  // Y region (bf16 hi/lo of tok)
  float* Yreg  = ws + off; off += (size_t)BS*NT*DD;
  unsigned short* Yh = (unsigned short*)Yreg;
  unsigned short* Yl = Yh + (size_t)BS*NT*DD;
  float* Gp    = ws + off; off += (size_t)BS*2*8*NT;
  float* avec  = ws + off; off += (size_t)BS*NI;
  float* bvec  = ws + off; off += (size_t)BS*NT;
  u32*   mm    = (u32*)(ws + off); off += 8;
  float* wd_b  = ws + off; off += BS;
  float* gwd_b = ws + off; off += BS;
  int*   flags = (int*)(ws + off); off += 6*BS;

  init_mm_k<<<1, 64, 0, stream>>>(mm);
  zero_k<<<1, 256, 0, stream>>>(flags, wd_b);

  // normalize + bf16 hi/lo split
  prep_k<<<dim3(NI,BS), 256, 0, stream>>>(img, nullptr, Xh, Xl, NI);
  prep_k<<<dim3(NT,BS), 256, 0, stream>>>(tok, tmsk,    Yh, Yl, NT);

  // cosine cost matrices via MFMA (Markidis split)
  cosmm_k<<<dim3(4, BS), 256, 0, stream>>>(Xh, Xl, Yh, Yl, cosIT, NI, NT, 2);
  cosmm_k<<<dim3(4, BS), 256, 0, stream>>>(Xh, Xl, Xh, Xl, Cs,    NI, NI, 2);
  cosmm_k<<<dim3(4, BS), 256, 0, stream>>>(Yh, Yl, Yh, Yl, Ct,    NT, NT, 2);

  // global min/max then threshold-relu (+mask for Cs/Ct)
  minmax_k<<<512, 256, 0, stream>>>(cosIT, (size_t)BS*NI*NT, mm+0);
  minmax_k<<<512, 256, 0, stream>>>(Cs,    (size_t)BS*NI*NI, mm+2);
  minmax_k<<<512, 256, 0, stream>>>(Ct,    (size_t)BS*NT*NT, mm+4);
  thresh_k<<<1024, 256, 0, stream>>>(cosIT, nullptr, (size_t)BS*NI*NT, mm+0);
  thresh_k<<<1024, 256, 0, stream>>>(Cs,    irm,     (size_t)BS*NI*NI, mm+2);
  thresh_k<<<1024, 256, 0, stream>>>(Ct,    tdm,     (size_t)BS*NT*NT, mm+4);

  // Cst components
  rowmeansq_k<<<dim3(NI,BS), 64, 0, stream>>>(Cs, avec, NI, NI);
  rowmeansq_k<<<dim3(NT,BS), 64, 0, stream>>>(Ct, bvec, NT, NT);

  // wd-IPOT (writes T_wd and wd partials)
  ipot8_k<true><<<dim3(8, BS), 256, 0, stream>>>(cosIT, out + 1, wd_b, Gp, flags);

  // GW
  fill_k<<<512, 256, 0, stream>>>(gamma, (size_t)BS*NI*NT, 1.0f/((float)NI*(float)NT));
  for (int itn = 0; itn < 6; ++itn){
    gemm_k<false,0><<<dim3((NI+63)/64,(NT+63)/64,BS), 256, 0, stream>>>(Cs, gamma, G1, NI, NT, NI, nullptr, nullptr);
    gemm_k<true,2><<<dim3((NI+63)/64,(NT+63)/64,BS), 256, 0, stream>>>(G1, Ct, Cgam, NI, NT, NT, avec, bvec);
    if (itn < 5)
      ipot8_k<false><<<dim3(8, BS), 256, 0, stream>>>(Cgam, gamma, nullptr, Gp, flags + (1+itn)*BS);
  }

  gwdist_k<<<BS, 256, 0, stream>>>(Cgam, gamma, out + 1 + (size_t)BS*NI*NT, gwd_b);
  fin_k<<<1, 64, 0, stream>>>(wd_b, gwd_b, out);
}

// Round 6
// 996.594 us; speedup vs baseline: 2.3378x; 2.3378x over previous
//
#include <hip/hip_runtime.h>
#include <math.h>

#define BS 32
#define NI 196
#define NT 256
#define DD 1024

typedef unsigned int u32;
typedef __attribute__((ext_vector_type(8))) short bf16x8;
typedef __attribute__((ext_vector_type(4))) float f32x4;

__device__ __forceinline__ u32 fenc(float f){ u32 u = __float_as_uint(f); return (u & 0x80000000u) ? ~u : (u | 0x80000000u); }
__device__ __forceinline__ float fdec(u32 u){ return __uint_as_float((u & 0x80000000u) ? (u & 0x7fffffffu) : ~u); }

// bf16 helpers (manual RNE)
__device__ __forceinline__ unsigned short f2bf(float f){
  u32 u = __float_as_uint(f);
  u32 r = (u + 0x7FFFu + ((u >> 16) & 1u)) >> 16;
  return (unsigned short)r;
}
__device__ __forceinline__ float bf2f(unsigned short h){ return __uint_as_float((u32)h << 16); }

template<int CTRL>
__device__ __forceinline__ float dppadd(float x){
  int y = __builtin_amdgcn_update_dpp(0, __float_as_int(x), CTRL, 0xF, 0xF, false);
  return x + __int_as_float(y);
}
// sum over each 32-lane half of the wave
__device__ __forceinline__ float rowsum32(float x){
  x = dppadd<0xB1>(x);    // quad_perm xor1
  x = dppadd<0x4E>(x);    // quad_perm xor2
  x = dppadd<0x141>(x);   // row_half_mirror (pairs within 8)
  x = dppadd<0x128>(x);   // row_ror:8 (pairs within 16)
  x += __shfl_xor(x, 16);
  return x;
}

// ---------------- init ----------------
__global__ void init_mm_k(u32* mm){
  int t = threadIdx.x;
  if (t < 3){ mm[2*t] = 0xFFFFFFFFu; mm[2*t+1] = 0u; }
}

// ---------------- prep: normalize rows, split to bf16 hi/lo ----------------
__global__ __launch_bounds__(256) void prep_k(const float* __restrict__ feat,
                                              const float* __restrict__ mask,
                                              unsigned short* __restrict__ hi,
                                              unsigned short* __restrict__ lo, int R){
  int b = blockIdx.y, r = blockIdx.x, t = threadIdx.x;
  size_t rowoff = ((size_t)b*R + r)*DD;
  float4 v = ((const float4*)(feat + rowoff))[t];
  float s = v.x*v.x + v.y*v.y + v.z*v.z + v.w*v.w;
  #pragma unroll
  for (int m = 32; m >= 1; m >>= 1) s += __shfl_xor(s, m);
  __shared__ float ps[4];
  if ((t & 63) == 0) ps[t >> 6] = s;
  __syncthreads();
  float tot = ps[0] + ps[1] + ps[2] + ps[3];
  float mv = mask ? mask[b*R + r] : 1.0f;
  float sc = mv / (mv * sqrtf(tot) + 1e-12f);
  float x[4] = {v.x*sc, v.y*sc, v.z*sc, v.w*sc};
  unsigned short h[4], l[4];
  #pragma unroll
  for (int i = 0; i < 4; ++i){
    h[i] = f2bf(x[i]);
    l[i] = f2bf(x[i] - bf2f(h[i]));
  }
  *(ushort4*)(hi + rowoff + t*4) = make_ushort4(h[0],h[1],h[2],h[3]);
  *(ushort4*)(lo + rowoff + t*4) = make_ushort4(l[0],l[1],l[2],l[3]);
}

// ---------------- MFMA cos GEMM: C = 1 - Xn . Yn^T (128x128 tile) ----------------
__global__ __launch_bounds__(256) void cosmm_k(const unsigned short* __restrict__ Xh,
                                               const unsigned short* __restrict__ Xl,
                                               const unsigned short* __restrict__ Yh,
                                               const unsigned short* __restrict__ Yl,
                                               float* __restrict__ C, int M, int N, int nTN){
  __shared__ unsigned short Ah[128*40], Al[128*40], Bh[128*40], Bl[128*40];
  int b = blockIdx.y;
  int tm = (blockIdx.x / nTN) * 128, tn = (blockIdx.x % nTN) * 128;
  int t = threadIdx.x, lane = t & 63, w = t >> 6;
  int wm = (w >> 1) * 64, wn = (w & 1) * 64;
  const unsigned short* Xhb = Xh + (size_t)b*M*DD;
  const unsigned short* Xlb = Xl + (size_t)b*M*DD;
  const unsigned short* Yhb = Yh + (size_t)b*N*DD;
  const unsigned short* Ylb = Yl + (size_t)b*N*DD;
  f32x4 acc[4][4];
  #pragma unroll
  for (int m = 0; m < 4; ++m)
    #pragma unroll
    for (int n = 0; n < 4; ++n) acc[m][n] = (f32x4){0.f,0.f,0.f,0.f};

  int sr0 = t >> 2, sc0 = (t & 3) * 8;
  int gr0 = min(tm + sr0, M-1),      gr1 = min(tm + sr0 + 64, M-1);
  int gc0 = min(tn + sr0, N-1),      gc1 = min(tn + sr0 + 64, N-1);
  const unsigned short* pa0 = Xhb + (size_t)gr0*DD + sc0;
  const unsigned short* pa1 = Xhb + (size_t)gr1*DD + sc0;
  const unsigned short* pa2 = Xlb + (size_t)gr0*DD + sc0;
  const unsigned short* pa3 = Xlb + (size_t)gr1*DD + sc0;
  const unsigned short* pb0 = Yhb + (size_t)gc0*DD + sc0;
  const unsigned short* pb1 = Yhb + (size_t)gc1*DD + sc0;
  const unsigned short* pb2 = Ylb + (size_t)gc0*DD + sc0;
  const unsigned short* pb3 = Ylb + (size_t)gc1*DD + sc0;
  int fr = lane & 15, fk = (lane >> 4) * 8;

  for (int k0 = 0; k0 < DD; k0 += 32){
    float4 a0 = *(const float4*)(pa0 + k0);
    float4 a1 = *(const float4*)(pa1 + k0);
    float4 a2 = *(const float4*)(pa2 + k0);
    float4 a3 = *(const float4*)(pa3 + k0);
    float4 b0 = *(const float4*)(pb0 + k0);
    float4 b1 = *(const float4*)(pb1 + k0);
    float4 b2 = *(const float4*)(pb2 + k0);
    float4 b3 = *(const float4*)(pb3 + k0);
    __syncthreads();
    *(float4*)&Ah[sr0*40 + sc0]      = a0;
    *(float4*)&Ah[(sr0+64)*40 + sc0] = a1;
    *(float4*)&Al[sr0*40 + sc0]      = a2;
    *(float4*)&Al[(sr0+64)*40 + sc0] = a3;
    *(float4*)&Bh[sr0*40 + sc0]      = b0;
    *(float4*)&Bh[(sr0+64)*40 + sc0] = b1;
    *(float4*)&Bl[sr0*40 + sc0]      = b2;
    *(float4*)&Bl[(sr0+64)*40 + sc0] = b3;
    __syncthreads();
    bf16x8 ah[4], al[4], bh[4], bl[4];
    #pragma unroll
    for (int m = 0; m < 4; ++m){
      int r = wm + m*16 + fr;
      ah[m] = *(bf16x8*)&Ah[r*40 + fk];
      al[m] = *(bf16x8*)&Al[r*40 + fk];
    }
    #pragma unroll
    for (int n = 0; n < 4; ++n){
      int r = wn + n*16 + fr;
      bh[n] = *(bf16x8*)&Bh[r*40 + fk];
      bl[n] = *(bf16x8*)&Bl[r*40 + fk];
    }
    #pragma unroll
    for (int m = 0; m < 4; ++m)
      #pragma unroll
      for (int n = 0; n < 4; ++n){
        acc[m][n] = __builtin_amdgcn_mfma_f32_16x16x32_bf16(ah[m], bh[n], acc[m][n], 0,0,0);
        acc[m][n] = __builtin_amdgcn_mfma_f32_16x16x32_bf16(ah[m], bl[n], acc[m][n], 0,0,0);
        acc[m][n] = __builtin_amdgcn_mfma_f32_16x16x32_bf16(al[m], bh[n], acc[m][n], 0,0,0);
      }
  }
  float* Cb = C + (size_t)b*M*N;
  #pragma unroll
  for (int m = 0; m < 4; ++m){
    int row0 = tm + wm + m*16 + ((lane >> 4) << 2);
    #pragma unroll
    for (int n = 0; n < 4; ++n){
      int col = tn + wn + n*16 + (lane & 15);
      if (col < N){
        #pragma unroll
        for (int r = 0; r < 4; ++r){
          int row = row0 + r;
          if (row < M) Cb[(size_t)row*N + col] = 1.0f - acc[m][n][r];
        }
      }
    }
  }
}

// ---------------- MFMA NT GEMM on pre-split bf16 operands (64x64 tile) ----------------
// C[i][j] = sum_k A[i][k]*B[j][k]  (3-term markidis). EPI: 0 plain, 2 -> av[i]+bv[j]-2x
template<int EPI>
__global__ __launch_bounds__(256) void mmnt_k(const unsigned short* __restrict__ Ah,
                                              const unsigned short* __restrict__ Al,
                                              const unsigned short* __restrict__ Bh,
                                              const unsigned short* __restrict__ Bl,
                                              float* __restrict__ C,
                                              int M, int N, int Kp, int nTN,
                                              const float* __restrict__ av,
                                              const float* __restrict__ bv){
  __shared__ unsigned short As_h[64*40], As_l[64*40], Bs_h[64*40], Bs_l[64*40];
  int b = blockIdx.y;
  int tm = (blockIdx.x / nTN) * 64, tn = (blockIdx.x % nTN) * 64;
  int t = threadIdx.x, lane = t & 63, w = t >> 6;
  int wm = (w >> 1) * 32, wn = (w & 1) * 32;
  const unsigned short* Ahb = Ah + (size_t)b*M*Kp;
  const unsigned short* Alb = Al + (size_t)b*M*Kp;
  const unsigned short* Bhb = Bh + (size_t)b*N*Kp;
  const unsigned short* Blb = Bl + (size_t)b*N*Kp;
  f32x4 acc[2][2];
  #pragma unroll
  for (int m = 0; m < 2; ++m)
    #pragma unroll
    for (int n = 0; n < 2; ++n) acc[m][n] = (f32x4){0.f,0.f,0.f,0.f};

  int srow = t >> 2, sch = (t & 3) * 8;
  int ga = min(tm + srow, M-1), gbn = min(tn + srow, N-1);
  const unsigned short* pah = Ahb + (size_t)ga*Kp + sch;
  const unsigned short* pal = Alb + (size_t)ga*Kp + sch;
  const unsigned short* pbh = Bhb + (size_t)gbn*Kp + sch;
  const unsigned short* pbl = Blb + (size_t)gbn*Kp + sch;
  int fr = lane & 15, fk = (lane >> 4) * 8;

  for (int k0 = 0; k0 < Kp; k0 += 32){
    float4 vah = *(const float4*)(pah + k0);
    float4 val = *(const float4*)(pal + k0);
    float4 vbh = *(const float4*)(pbh + k0);
    float4 vbl = *(const float4*)(pbl + k0);
    __syncthreads();
    *(float4*)&As_h[srow*40 + sch] = vah;
    *(float4*)&As_l[srow*40 + sch] = val;
    *(float4*)&Bs_h[srow*40 + sch] = vbh;
    *(float4*)&Bs_l[srow*40 + sch] = vbl;
    __syncthreads();
    bf16x8 fah[2], fal[2], fbh[2], fbl[2];
    #pragma unroll
    for (int m = 0; m < 2; ++m){
      int r = wm + m*16 + fr;
      fah[m] = *(bf16x8*)&As_h[r*40 + fk];
      fal[m] = *(bf16x8*)&As_l[r*40 + fk];
    }
    #pragma unroll
    for (int n = 0; n < 2; ++n){
      int r = wn + n*16 + fr;
      fbh[n] = *(bf16x8*)&Bs_h[r*40 + fk];
      fbl[n] = *(bf16x8*)&Bs_l[r*40 + fk];
    }
    #pragma unroll
    for (int m = 0; m < 2; ++m)
      #pragma unroll
      for (int n = 0; n < 2; ++n){
        acc[m][n] = __builtin_amdgcn_mfma_f32_16x16x32_bf16(fah[m], fbh[n], acc[m][n], 0,0,0);
        acc[m][n] = __builtin_amdgcn_mfma_f32_16x16x32_bf16(fah[m], fbl[n], acc[m][n], 0,0,0);
        acc[m][n] = __builtin_amdgcn_mfma_f32_16x16x32_bf16(fal[m], fbh[n], acc[m][n], 0,0,0);
      }
  }
  float* Cb = C + (size_t)b*M*N;
  #pragma unroll
  for (int m = 0; m < 2; ++m){
    int row0 = tm + wm + m*16 + ((lane >> 4) << 2);
    #pragma unroll
    for (int n = 0; n < 2; ++n){
      int col = tn + wn + n*16 + (lane & 15);
      #pragma unroll
      for (int r = 0; r < 4; ++r){
        int row = row0 + r;
        if (row < M){
          float x = acc[m][n][r];
          if (EPI == 2) x = av[b*M + row] + bv[b*N + col] - 2.0f*x;
          Cb[(size_t)row*N + col] = x;
        }
      }
    }
  }
}

// ---------------- plain bf16 hi/lo split with K zero-padding ----------------
// src [R][Cin] fp32 -> dsth/dstl [R][Kp] (cols >= Cin zeroed). grid (R, BS), 256 thr.
__global__ __launch_bounds__(256) void split_k(const float* __restrict__ src,
                                               unsigned short* __restrict__ dsth,
                                               unsigned short* __restrict__ dstl,
                                               int Cin, int Kp){
  int r = blockIdx.x, b = blockIdx.y, j = threadIdx.x, R = gridDim.x;
  if (j >= Kp) return;
  float v = (j < Cin) ? src[((size_t)b*R + r)*Cin + j] : 0.f;
  unsigned short h = f2bf(v);
  unsigned short l = f2bf(v - bf2f(h));
  size_t o = ((size_t)b*R + r)*Kp + j;
  dsth[o] = h; dstl[o] = l;
}

// ---------------- transpose + split: gamma [196][256] -> gT h/l [256][224] ----------------
// grid (8 j-tiles, 7 k-tiles, BS), 256 thr, 32x32 tiles via LDS.
__global__ __launch_bounds__(256) void splitT_k(const float* __restrict__ g,
                                                unsigned short* __restrict__ th,
                                                unsigned short* __restrict__ tl){
  __shared__ float tile[32][33];
  int j0 = blockIdx.x * 32, k0 = blockIdx.y * 32, b = blockIdx.z;
  int t = threadIdx.x;
  const float* gb = g + (size_t)b*NI*NT;
  {
    int a = t >> 3, ch = t & 7;            // row k0+a, cols j0+4ch..+3
    int k = k0 + a;
    float4 v = make_float4(0.f,0.f,0.f,0.f);
    if (k < NI) v = *(const float4*)(gb + (size_t)k*NT + j0 + ch*4);
    tile[a][ch*4+0] = v.x; tile[a][ch*4+1] = v.y; tile[a][ch*4+2] = v.z; tile[a][ch*4+3] = v.w;
  }
  __syncthreads();
  {
    int jloc = t >> 3, ch = t & 7;         // out row j0+jloc, cols k0+4ch..+3
    int j = j0 + jloc;
    unsigned short h[4], l[4];
    #pragma unroll
    for (int r = 0; r < 4; ++r){
      float v = tile[ch*4 + r][jloc];
      h[r] = f2bf(v);
      l[r] = f2bf(v - bf2f(h[r]));
    }
    size_t o = ((size_t)b*NT + j)*224 + k0 + ch*4;
    *(ushort4*)(th + o) = make_ushort4(h[0],h[1],h[2],h[3]);
    *(ushort4*)(tl + o) = make_ushort4(l[0],l[1],l[2],l[3]);
  }
}

// ---------------- global min/max ----------------
__global__ __launch_bounds__(256) void minmax_k(const float* __restrict__ X, size_t cnt, u32* __restrict__ mm){
  size_t stride = (size_t)gridDim.x * blockDim.x;
  float mn = 3.402823466e38f, mx = -3.402823466e38f;
  for (size_t i = (size_t)blockIdx.x*blockDim.x + threadIdx.x; i < cnt; i += stride){
    float v = X[i]; mn = fminf(mn, v); mx = fmaxf(mx, v);
  }
  #pragma unroll
  for (int m = 32; m >= 1; m >>= 1){ mn = fminf(mn, __shfl_xor(mn, m)); mx = fmaxf(mx, __shfl_xor(mx, m)); }
  __shared__ float smn[4], smx[4];
  int t = threadIdx.x;
  if ((t & 63) == 0){ smn[t>>6] = mn; smx[t>>6] = mx; }
  __syncthreads();
  if (t == 0){
    mn = fminf(fminf(smn[0], smn[1]), fminf(smn[2], smn[3]));
    mx = fmaxf(fmaxf(smx[0], smx[1]), fmaxf(smx[2], smx[3]));
    atomicMin(&mm[0], fenc(mn));
    atomicMax(&mm[1], fenc(mx));
  }
}

// ---------------- threshold-relu (+ optional {0,1}->{1e-5,1} mask) ----------------
__global__ __launch_bounds__(256) void thresh_k(float* __restrict__ X, const int* __restrict__ msk,
                                                size_t cnt, const u32* __restrict__ mm){
  float mn = fdec(mm[0]), mx = fdec(mm[1]);
  float thr = mn + 0.1f * (mx - mn);
  size_t stride = (size_t)gridDim.x * blockDim.x;
  for (size_t i = (size_t)blockIdx.x*blockDim.x + threadIdx.x; i < cnt; i += stride){
    float v = X[i] - thr;
    v = v > 0.f ? v : 0.f;
    if (msk) v *= (msk[i] == 1 ? 1.0f : 1e-5f);
    X[i] = v;
  }
}

// ---------------- row mean of squares ----------------
__global__ __launch_bounds__(64) void rowmeansq_k(const float* __restrict__ X, float* __restrict__ out, int R, int Cc){
  int b = blockIdx.y, r = blockIdx.x, t = threadIdx.x;
  const float* row = X + ((size_t)b*R + r) * Cc;
  float s = 0.f;
  for (int j = t; j < Cc; j += 64){ float v = row[j]; s = fmaf(v, v, s); }
  #pragma unroll
  for (int m = 32; m >= 1; m >>= 1) s += __shfl_xor(s, m);
  if (t == 0) out[b*R + r] = s / (float)Cc;
}

// ---------------- fill ----------------
__global__ void fill_k(float* __restrict__ X, size_t cnt, float val){
  size_t stride = (size_t)gridDim.x * blockDim.x;
  for (size_t i = (size_t)blockIdx.x*blockDim.x + threadIdx.x; i < cnt; i += stride) X[i] = val;
}

// ---------------- IPOT: register-resident C and T, P=exp(-2C) recomputed ----------------
// One block (512 thr = 8 waves) per batch. thread: c=t&31 (cols j=c+32l, l<8),
// R=t>>5 (rows i=R+16k, k<13; k==12 masked to i<196).
// Register budget: C 104 + T 104 + ~30 working < 256 (launch_bounds(512,2)) -> NO scratch
// spill. r1/r2/r5 all spilled P/T to scratch (VGPR_Count 128/64/52 vs 200+ live floats)
// and were spill-traffic-bound at an invariant ~107us.
template<bool WD>
__global__ __launch_bounds__(512, 2) void ipotr_k(const float* __restrict__ Cmat,
                                                  float* __restrict__ Tout,
                                                  float* __restrict__ distBuf){
  __shared__ float cp[16][NT];
  __shared__ float sgm[NT];
  __shared__ float wp[8];
  int b = blockIdx.x, t = threadIdx.x;
  int c = t & 31, R = t >> 5;
  const float* Cb = Cmat + (size_t)b * NI * NT;
  bool ok12 = (R < 4);                     // row 192+R valid iff R<4 (196 rows)
  float Cv[13][8], T[13][8];
  #pragma unroll
  for (int k = 0; k < 13; ++k){
    int i = R + 16*k;
    bool ok = (k < 12) | ok12;
    #pragma unroll
    for (int l = 0; l < 8; ++l){
      Cv[k][l] = ok ? Cb[(size_t)i*NT + c + 32*l] : 1.0e3f;   // exp(-2e3) = 0
      T[k][l]  = ok ? 1.f : 0.f;
    }
  }
  float sl[8];
  #pragma unroll
  for (int l = 0; l < 8; ++l) sl[l] = 1.0f / (float)NT;

  for (int it = 0; it < 20; ++it){
    float cpl[8];
    #pragma unroll
    for (int l = 0; l < 8; ++l) cpl[l] = 0.f;
    #pragma unroll
    for (int k = 0; k < 13; ++k){
      float a = 0.f;
      #pragma unroll
      for (int l = 0; l < 8; ++l){
        float q = __expf(-2.0f * Cv[k][l]) * T[k][l];   // Q = P (.) T
        T[k][l] = q;
        a = fmaf(q, sl[l], a);                          // row partial of Q*sigma
      }
      a = rowsum32(a);
      float dl = __builtin_amdgcn_rcpf((float)NI * a);  // delta_i
      if (k == 12) dl = ok12 ? dl : 0.f;                // dead rows: avoid 0*inf
      #pragma unroll
      for (int l = 0; l < 8; ++l){
        T[k][l] *= dl;                                  // fold delta into T
        cpl[l] += T[k][l];                              // col partial of Q*delta
      }
    }
    #pragma unroll
    for (int l = 0; l < 8; ++l) cp[R][c + 32*l] = cpl[l];   // bank c: conflict-free
    __syncthreads();
    if (t < NT){
      float s = 0.f;
      #pragma unroll
      for (int g = 0; g < 16; ++g) s += cp[g][t];           // bank t%32: conflict-free
      sgm[t] = __builtin_amdgcn_rcpf((float)NT * s);        // sigma_j
    }
    __syncthreads();
    #pragma unroll
    for (int l = 0; l < 8; ++l) sl[l] = sgm[c + 32*l];
    #pragma unroll
    for (int k = 0; k < 13; ++k)
      #pragma unroll
      for (int l = 0; l < 8; ++l) T[k][l] *= sl[l];         // T = delta*Q*sigma
  }
  float* To = Tout + (size_t)b * NI * NT;
  #pragma unroll
  for (int k = 0; k < 13; ++k){
    int i = R + 16*k;
    if ((k < 12) | ok12){
      #pragma unroll
      for (int l = 0; l < 8; ++l) To[(size_t)i*NT + c + 32*l] = T[k][l];
    }
  }
  if (WD){
    float a = 0.f;
    #pragma unroll
    for (int k = 0; k < 13; ++k)
      #pragma unroll
      for (int l = 0; l < 8; ++l) a = fmaf(Cv[k][l] < 5.0e2f ? Cv[k][l] : 0.f, T[k][l], a);
    #pragma unroll
    for (int m = 32; m >= 1; m >>= 1) a += __shfl_xor(a, m);
    if ((t & 63) == 0) wp[t >> 6] = a;
    __syncthreads();
    if (t == 0){
      float s = 0.f;
      #pragma unroll
      for (int g = 0; g < 8; ++g) s += wp[g];
      distBuf[b] = -s;
    }
  }
}

// ---------------- GW final distance + copy gamma to output ----------------
__global__ __launch_bounds__(256) void gwdist_k(const float* __restrict__ Cg, const float* __restrict__ gam,
                                                float* __restrict__ outT, float* __restrict__ gwd){
  int b = blockIdx.x, t = threadIdx.x;
  const float* cb = Cg + (size_t)b*NI*NT;
  const float* gb = gam + (size_t)b*NI*NT;
  float* ob = outT + (size_t)b*NI*NT;
  float a = 0.f;
  for (int i = t; i < NI*NT; i += 256){
    float g = gb[i];
    a = fmaf(cb[i], g, a);
    ob[i] = g;
  }
  #pragma unroll
  for (int m = 32; m >= 1; m >>= 1) a += __shfl_xor(a, m);
  __shared__ float ps[4];
  if ((t & 63) == 0) ps[t>>6] = a;
  __syncthreads();
  if (t == 0) gwd[b] = ps[0]+ps[1]+ps[2]+ps[3];
}

// ---------------- final scalar ----------------
__global__ void fin_k(const float* __restrict__ wd, const float* __restrict__ gwd, float* __restrict__ out){
  int t = threadIdx.x;
  float w = (t < BS) ? wd[t] : 0.f;
  float g = (t < BS) ? gwd[t] : 0.f;
  #pragma unroll
  for (int m = 32; m >= 1; m >>= 1){ w += __shfl_xor(w, m); g += __shfl_xor(g, m); }
  if (t == 0) out[0] = 0.1f * (g / (float)BS) + 0.1f * (w / (float)BS);
}

extern "C" void kernel_launch(void* const* d_in, const int* in_sizes, int n_in,
                              void* d_out, int out_size, void* d_ws, size_t ws_size,
                              hipStream_t stream){
  const float* img  = (const float*)d_in[0];   // (32,196,1024)
  const float* tok  = (const float*)d_in[1];   // (32,256,1024)
  const float* tmsk = (const float*)d_in[2];   // (32,256)
  const int*   tdm  = (const int*)d_in[3];     // (32,256,256)
  const int*   irm  = (const int*)d_in[4];     // (32,196,196)
  float* out = (float*)d_out;                  // [twd, T_wd, T_gwd]

  float* ws = (float*)d_ws;
  size_t off = 0;
  float* cosIT = ws + off; off += (size_t)BS*NI*NT;
  float* Cs    = ws + off; off += (size_t)BS*NI*NI;
  float* Ct    = ws + off; off += (size_t)BS*NT*NT;
  // X region: bf16 hi/lo of img for cosmm; later aliased by gamma/Cgam/G1
  float* Xreg  = ws + off; off += (size_t)BS*NI*DD;           // 6.42M floats
  float* gamma = Xreg;
  float* Cgam  = Xreg + (size_t)BS*NI*NT;
  float* G1    = Xreg + (size_t)2*BS*NI*NT;                   // 4.8M <= 6.42M ok
  unsigned short* Xh = (unsigned short*)Xreg;
  unsigned short* Xl = Xh + (size_t)BS*NI*DD;
  // Y region: bf16 hi/lo of tok; later aliased by GW split buffers
  float* Yreg  = ws + off; off += (size_t)BS*NT*DD;           // 8.39M floats
  unsigned short* Yh = (unsigned short*)Yreg;
  unsigned short* Yl = Yh + (size_t)BS*NT*DD;
  {
    // GW split buffers (alias Y region after cos GEMMs): need 6.94M float-slots
  }
  unsigned short* Csh = (unsigned short*)Yreg;                        // 32*196*224
  unsigned short* Csl = Csh + (size_t)BS*NI*224;
  unsigned short* Cth = Csl + (size_t)BS*NI*224;                      // 32*256*256
  unsigned short* Ctl = Cth + (size_t)BS*NT*256;
  unsigned short* gTh = Ctl + (size_t)BS*NT*256;                      // 32*256*224
  unsigned short* gTl = gTh + (size_t)BS*NT*224;
  unsigned short* G1h = gTl + (size_t)BS*NT*224;                      // 32*196*256
  unsigned short* G1l = G1h + (size_t)BS*NI*256;
  float* avec  = ws + off; off += (size_t)BS*NI;
  float* bvec  = ws + off; off += (size_t)BS*NT;
  u32*   mm    = (u32*)(ws + off); off += 8;
  float* wd_b  = ws + off; off += BS;
  float* gwd_b = ws + off; off += BS;

  init_mm_k<<<1, 64, 0, stream>>>(mm);

  // normalize + bf16 hi/lo split
  prep_k<<<dim3(NI,BS), 256, 0, stream>>>(img, nullptr, Xh, Xl, NI);
  prep_k<<<dim3(NT,BS), 256, 0, stream>>>(tok, tmsk,    Yh, Yl, NT);

  // cosine cost matrices via MFMA (Markidis split)
  cosmm_k<<<dim3(4, BS), 256, 0, stream>>>(Xh, Xl, Yh, Yl, cosIT, NI, NT, 2);
  cosmm_k<<<dim3(4, BS), 256, 0, stream>>>(Xh, Xl, Xh, Xl, Cs,    NI, NI, 2);
  cosmm_k<<<dim3(4, BS), 256, 0, stream>>>(Yh, Yl, Yh, Yl, Ct,    NT, NT, 2);

  // global min/max then threshold-relu (+mask for Cs/Ct)
  minmax_k<<<512, 256, 0, stream>>>(cosIT, (size_t)BS*NI*NT, mm+0);
  minmax_k<<<512, 256, 0, stream>>>(Cs,    (size_t)BS*NI*NI, mm+2);
  minmax_k<<<512, 256, 0, stream>>>(Ct,    (size_t)BS*NT*NT, mm+4);
  thresh_k<<<1024, 256, 0, stream>>>(cosIT, nullptr, (size_t)BS*NI*NT, mm+0);
  thresh_k<<<1024, 256, 0, stream>>>(Cs,    irm,     (size_t)BS*NI*NI, mm+2);
  thresh_k<<<1024, 256, 0, stream>>>(Ct,    tdm,     (size_t)BS*NT*NT, mm+4);

  // Cst components
  rowmeansq_k<<<dim3(NI,BS), 64, 0, stream>>>(Cs, avec, NI, NI);
  rowmeansq_k<<<dim3(NT,BS), 64, 0, stream>>>(Ct, bvec, NT, NT);

  // one-time bf16 splits of thresholded Cs (K-pad 224) and Ct (K=256)
  // (Y region is dead from here on: cos GEMMs done)
  split_k<<<dim3(NI,BS), 256, 0, stream>>>(Cs, Csh, Csl, NI, 224);
  split_k<<<dim3(NT,BS), 256, 0, stream>>>(Ct, Cth, Ctl, NT, 256);

  // wd-IPOT (writes T_wd and wd)
  ipotr_k<true><<<BS, 512, 0, stream>>>(cosIT, out + 1, wd_b);

  // GW loop
  fill_k<<<512, 256, 0, stream>>>(gamma, (size_t)BS*NI*NT, 1.0f/((float)NI*(float)NT));
  for (int itn = 0; itn < 6; ++itn){
    splitT_k<<<dim3(8, 7, BS), 256, 0, stream>>>(gamma, gTh, gTl);
    mmnt_k<0><<<dim3(16, BS), 256, 0, stream>>>(Csh, Csl, gTh, gTl, G1, NI, NT, 224, 4, nullptr, nullptr);
    split_k<<<dim3(NI,BS), 256, 0, stream>>>(G1, G1h, G1l, NT, 256);
    mmnt_k<2><<<dim3(16, BS), 256, 0, stream>>>(G1h, G1l, Cth, Ctl, Cgam, NI, NT, 256, 4, avec, bvec);
    if (itn < 5)
      ipotr_k<false><<<BS, 512, 0, stream>>>(Cgam, gamma, nullptr);
  }

  gwdist_k<<<BS, 256, 0, stream>>>(Cgam, gamma, out + 1 + (size_t)BS*NI*NT, gwd_b);
  fin_k<<<1, 64, 0, stream>>>(wd_b, gwd_b, out);
}